// Round 1
// baseline (4549.230 us; speedup 1.0000x reference)
//
#include <hip/hip_runtime.h>
#include <hip/hip_bf16.h>
#include <math.h>

// Elman RNN fused kernel.
// Shapes: x[B=128, S=2048, I=128] fp32, W_in[H=256, I=128], b_in[H],
//         W_rec[H=256, H=256], W_out[O=128, H=256], b_out[O]. out[B, O] fp32.
//
// Design: one block per batch element (the only parallel axis of the scan).
// 256 threads; thread j owns hidden unit j and keeps W_in row j (32 float4)
// and W_rec row j (64 float4) in registers (~384 VGPRs, 1 wave/SIMD — fine,
// we only ever run 1 block/CU). h and the current x-row live in
// double-buffered LDS; every LDS read is wave-uniform (broadcast, no bank
// conflicts). One __syncthreads per timestep. x[t+1] prefetched during
// step t. Output projection fused at the end.

#define BATCH 128
#define SEQ   2048
#define NIN   128
#define NH    256
#define NOUT  128

__global__ __launch_bounds__(256, 1)
void elman_fused(const float* __restrict__ x,
                 const float* __restrict__ W_in,
                 const float* __restrict__ b_in,
                 const float* __restrict__ W_rec,
                 const float* __restrict__ W_out,
                 const float* __restrict__ b_out,
                 float* __restrict__ out) {
    const int b = blockIdx.x;
    const int j = threadIdx.x;  // hidden row 0..255

    __shared__ float4 hbuf[2][NH / 4];   // 2 x 1 KB
    __shared__ float4 xbuf[2][NIN / 4];  // 2 x 512 B

    // ---- load weights into registers (one-time; served from L2/L3) ----
    float4 win[NIN / 4];   // 32 float4 = 128 VGPRs
    float4 wrec[NH / 4];   // 64 float4 = 256 VGPRs
    {
        const float4* p = (const float4*)(W_in + j * NIN);
        #pragma unroll
        for (int i = 0; i < NIN / 4; ++i) win[i] = p[i];
        const float4* q = (const float4*)(W_rec + j * NH);
        #pragma unroll
        for (int i = 0; i < NH / 4; ++i) wrec[i] = q[i];
    }
    const float bj = b_in[j];

    // ---- init h0 = 0 and stage x[:,0,:] ----
    ((float*)hbuf[0])[j] = 0.0f;
    if (j < NIN) ((float*)xbuf[0])[j] = x[(size_t)(b * SEQ) * NIN + j];
    __syncthreads();

    // ---- sequential scan over t ----
    #pragma unroll 1
    for (int t = 0; t < SEQ; ++t) {
        const int cur = t & 1;
        const int nxt = cur ^ 1;

        // prefetch next timestep's x row (latency hidden by this step's FMAs)
        float xpre = 0.0f;
        if (j < NIN && t + 1 < SEQ)
            xpre = x[((size_t)b * SEQ + (t + 1)) * NIN + j];

        float4 acc = {0.f, 0.f, 0.f, 0.f};

        // input projection: dot(W_in[j,:], x_t)
        #pragma unroll
        for (int i = 0; i < NIN / 4; ++i) {
            float4 xv = xbuf[cur][i];  // wave-uniform broadcast read
            acc.x = fmaf(win[i].x, xv.x, acc.x);
            acc.y = fmaf(win[i].y, xv.y, acc.y);
            acc.z = fmaf(win[i].z, xv.z, acc.z);
            acc.w = fmaf(win[i].w, xv.w, acc.w);
        }
        // recurrent projection: dot(W_rec[j,:], h)
        #pragma unroll
        for (int i = 0; i < NH / 4; ++i) {
            float4 hv = hbuf[cur][i];  // wave-uniform broadcast read
            acc.x = fmaf(wrec[i].x, hv.x, acc.x);
            acc.y = fmaf(wrec[i].y, hv.y, acc.y);
            acc.z = fmaf(wrec[i].z, hv.z, acc.z);
            acc.w = fmaf(wrec[i].w, hv.w, acc.w);
        }

        float val = (acc.x + acc.y) + (acc.z + acc.w) + bj;
        float hnew = 1.0f / (1.0f + __expf(-val));

        ((float*)hbuf[nxt])[j] = hnew;
        if (j < NIN && t + 1 < SEQ) ((float*)xbuf[nxt])[j] = xpre;
        __syncthreads();
    }

    // After t = 2047 (cur=1, nxt=0) the final h sits in hbuf[0].
    // ---- fused output projection: out[b,o] = dot(W_out[o,:], h) + b_out[o]
    if (j < NOUT) {
        const float4* wo = (const float4*)(W_out + j * NH);
        float4 acc = {0.f, 0.f, 0.f, 0.f};
        #pragma unroll
        for (int i = 0; i < NH / 4; ++i) {
            float4 hv = hbuf[0][i];
            acc.x = fmaf(wo[i].x, hv.x, acc.x);
            acc.y = fmaf(wo[i].y, hv.y, acc.y);
            acc.z = fmaf(wo[i].z, hv.z, acc.z);
            acc.w = fmaf(wo[i].w, hv.w, acc.w);
        }
        out[b * NOUT + j] = (acc.x + acc.y) + (acc.z + acc.w) + b_out[j];
    }
}

extern "C" void kernel_launch(void* const* d_in, const int* in_sizes, int n_in,
                              void* d_out, int out_size, void* d_ws, size_t ws_size,
                              hipStream_t stream) {
    const float* x     = (const float*)d_in[0];
    const float* W_in  = (const float*)d_in[1];
    const float* b_in  = (const float*)d_in[2];
    const float* W_rec = (const float*)d_in[3];
    const float* W_out = (const float*)d_in[4];
    const float* b_out = (const float*)d_in[5];
    float* out = (float*)d_out;

    elman_fused<<<BATCH, 256, 0, stream>>>(x, W_in, b_in, W_rec, W_out, b_out, out);
}

// Round 2
// 2614.309 us; speedup vs baseline: 1.7401x; 1.7401x over previous
//
#include <hip/hip_runtime.h>
#include <hip/hip_bf16.h>

// Elman RNN via MFMA. Step t: H'[b,j] = sigmoid(x_t W_in^T + b_in + H W_rec^T)[b,j].
// Computed TRANSPOSED: C[m=hidden, n=batch] = W[m,:] . h^T[:,n], so that the
// MFMA C/D layout (col=lane&15=batch, row=(lane>>4)*4+reg=hidden) writes 4
// consecutive-hidden bf16 per lane (ds_write_b64) into an LDS layout
// [batch][hidden] that the next step's B-fragment (n=lane&15=batch,
// k=(lane>>4)*8+j=hidden, 16B contiguous) reads back with ds_read_b128.
//
// 8 blocks x 16 batch rows (batch = only parallel axis of the scan).
// 256 threads = 4 waves, wave w owns hidden m-tiles 4w..4w+3.
// W_rec/W_in A-fragments live in registers (~192 VGPRs). One barrier/step.
// LDS rows padded +8 bf16 so consecutive-8-lane groups hit distinct banks.

#define BATCH 128
#define SEQ   2048
#define NIN   128
#define NH    256
#define NOUT  128

#define BTILE 16
#define NBLK  (BATCH / BTILE)      // 8
#define HPITCH 264                 // 256 + 8 pad (bf16 elems)
#define XPITCH 136                 // 128 + 8 pad

typedef __attribute__((ext_vector_type(8))) short short8;
typedef __attribute__((ext_vector_type(4))) float f32x4;

__device__ __forceinline__ ushort f2bf(float f) {
    union { float f; uint u; } v; v.f = f;
    uint r = v.u + 0x7fffu + ((v.u >> 16) & 1u);   // round-to-nearest-even
    return (ushort)(r >> 16);
}

// Load an 8-wide (along k) bf16 A-fragment from an fp32 row-major matrix.
__device__ __forceinline__ short8 load_wfrag(const float* __restrict__ W, int ld,
                                             int row, int col) {
    const float4* p = (const float4*)(W + (size_t)row * ld + col);
    float4 a = p[0], b = p[1];
    union { short8 v; ushort u[8]; } r;
    r.u[0] = f2bf(a.x); r.u[1] = f2bf(a.y); r.u[2] = f2bf(a.z); r.u[3] = f2bf(a.w);
    r.u[4] = f2bf(b.x); r.u[5] = f2bf(b.y); r.u[6] = f2bf(b.z); r.u[7] = f2bf(b.w);
    return r.v;
}

__global__ __launch_bounds__(256, 1)
void elman_mfma(const float* __restrict__ x,
                const float* __restrict__ W_in,
                const float* __restrict__ b_in,
                const float* __restrict__ W_rec,
                const float* __restrict__ W_out,
                const float* __restrict__ b_out,
                float* __restrict__ out) {
    const int tid  = threadIdx.x;
    const int lane = tid & 63;
    const int wid  = tid >> 6;          // 0..3
    const int n15  = lane & 15;         // batch col within tile / B-frag n
    const int q    = lane >> 4;         // 0..3  (k-quad / row-quad)
    const int bblk = blockIdx.x * BTILE;

    __shared__ __align__(16) ushort hlds[2][BTILE * HPITCH];  // 2 x 8448 B
    __shared__ __align__(16) ushort xlds[2][BTILE * XPITCH];  // 2 x 4352 B

    // ---- one-time: A-fragments of W_rec / W_in into registers ----
    short8 wrec[4][8];   // [m-tile][k-tile]
    short8 win[4][4];
    float  bias[4][4];   // [m-tile][reg]
    #pragma unroll
    for (int mt = 0; mt < 4; ++mt) {
        const int row = (wid * 4 + mt) * 16 + n15;
        #pragma unroll
        for (int kt = 0; kt < 8; ++kt)
            wrec[mt][kt] = load_wfrag(W_rec, NH, row, kt * 32 + q * 8);
        #pragma unroll
        for (int kt = 0; kt < 4; ++kt)
            win[mt][kt] = load_wfrag(W_in, NIN, row, kt * 32 + q * 8);
        #pragma unroll
        for (int r = 0; r < 4; ++r)
            bias[mt][r] = b_in[(wid * 4 + mt) * 16 + q * 4 + r];
    }

    // ---- init: h0 = 0; stage x_0 into xlds[0] ----
    for (int i = tid; i < BTILE * HPITCH / 2; i += 256)
        ((uint*)hlds[0])[i] = 0u;

    const int xr = tid >> 4;            // batch row 0..15
    const int xc = (tid & 15) * 8;      // input col group
    const size_t xbase = ((size_t)(bblk + xr)) * SEQ * NIN + xc;
    {
        const float4* p = (const float4*)(x + xbase);
        float4 a = p[0], b = p[1];
        union { uint4 u4; ushort s[8]; } px;
        px.s[0] = f2bf(a.x); px.s[1] = f2bf(a.y); px.s[2] = f2bf(a.z); px.s[3] = f2bf(a.w);
        px.s[4] = f2bf(b.x); px.s[5] = f2bf(b.y); px.s[6] = f2bf(b.z); px.s[7] = f2bf(b.w);
        *(uint4*)&xlds[0][xr * XPITCH + xc] = px.u4;
    }
    __syncthreads();

    // ---- sequential scan ----
    #pragma unroll 1
    for (int t = 0; t < SEQ; ++t) {
        const int cur = t & 1, nxt = cur ^ 1;

        // global prefetch of x_{t+1} (off the critical path)
        float4 xp0{}, xp1{};
        if (t + 1 < SEQ) {
            const float4* p = (const float4*)(x + xbase + (size_t)(t + 1) * NIN);
            xp0 = p[0]; xp1 = p[1];
        }

        // B-fragments: x_t (4 k-tiles) and h_t (8 k-tiles)
        short8 bx[4], bh[8];
        #pragma unroll
        for (int kt = 0; kt < 4; ++kt)
            bx[kt] = *(const short8*)&xlds[cur][n15 * XPITCH + kt * 32 + q * 8];
        #pragma unroll
        for (int kt = 0; kt < 8; ++kt)
            bh[kt] = *(const short8*)&hlds[cur][n15 * HPITCH + kt * 32 + q * 8];

        // C init = b_in, then input-projection + recurrent MFMAs
        f32x4 acc[4];
        #pragma unroll
        for (int mt = 0; mt < 4; ++mt) {
            acc[mt][0] = bias[mt][0]; acc[mt][1] = bias[mt][1];
            acc[mt][2] = bias[mt][2]; acc[mt][3] = bias[mt][3];
        }
        #pragma unroll
        for (int kt = 0; kt < 4; ++kt)
            #pragma unroll
            for (int mt = 0; mt < 4; ++mt)
                acc[mt] = __builtin_amdgcn_mfma_f32_16x16x32_bf16(
                    win[mt][kt], bx[kt], acc[mt], 0, 0, 0);
        #pragma unroll
        for (int kt = 0; kt < 8; ++kt)
            #pragma unroll
            for (int mt = 0; mt < 4; ++mt)
                acc[mt] = __builtin_amdgcn_mfma_f32_16x16x32_bf16(
                    wrec[mt][kt], bh[kt], acc[mt], 0, 0, 0);

        // sigmoid + pack + write h_{t+1} (4 consecutive hidden per lane)
        #pragma unroll
        for (int mt = 0; mt < 4; ++mt) {
            float h0 = 1.0f / (1.0f + __expf(-acc[mt][0]));
            float h1 = 1.0f / (1.0f + __expf(-acc[mt][1]));
            float h2 = 1.0f / (1.0f + __expf(-acc[mt][2]));
            float h3 = 1.0f / (1.0f + __expf(-acc[mt][3]));
            uint2 w;
            w.x = (uint)f2bf(h0) | ((uint)f2bf(h1) << 16);
            w.y = (uint)f2bf(h2) | ((uint)f2bf(h3) << 16);
            *(uint2*)&hlds[nxt][n15 * HPITCH + (wid * 4 + mt) * 16 + q * 4] = w;
        }

        // stage x_{t+1} into the other x buffer
        if (t + 1 < SEQ) {
            union { uint4 u4; ushort s[8]; } px;
            px.s[0] = f2bf(xp0.x); px.s[1] = f2bf(xp0.y);
            px.s[2] = f2bf(xp0.z); px.s[3] = f2bf(xp0.w);
            px.s[4] = f2bf(xp1.x); px.s[5] = f2bf(xp1.y);
            px.s[6] = f2bf(xp1.z); px.s[7] = f2bf(xp1.w);
            *(uint4*)&xlds[nxt][xr * XPITCH + xc] = px.u4;
        }
        __syncthreads();
    }

    // ---- output projection: out^T[o,b] = W_out[o,:] . h_fin^T ----
    // final h is in hlds[0] (SEQ even). 128 outputs = 8 m-tiles / 4 waves.
    short8 wout[2][8];
    float  bo[2][4];
    #pragma unroll
    for (int mo = 0; mo < 2; ++mo) {
        const int row = (wid * 2 + mo) * 16 + n15;
        #pragma unroll
        for (int kt = 0; kt < 8; ++kt)
            wout[mo][kt] = load_wfrag(W_out, NH, row, kt * 32 + q * 8);
        #pragma unroll
        for (int r = 0; r < 4; ++r)
            bo[mo][r] = b_out[(wid * 2 + mo) * 16 + q * 4 + r];
    }
    f32x4 oacc[2];
    #pragma unroll
    for (int mo = 0; mo < 2; ++mo) {
        oacc[mo][0] = bo[mo][0]; oacc[mo][1] = bo[mo][1];
        oacc[mo][2] = bo[mo][2]; oacc[mo][3] = bo[mo][3];
    }
    #pragma unroll
    for (int kt = 0; kt < 8; ++kt) {
        short8 bh = *(const short8*)&hlds[0][n15 * HPITCH + kt * 32 + q * 8];
        #pragma unroll
        for (int mo = 0; mo < 2; ++mo)
            oacc[mo] = __builtin_amdgcn_mfma_f32_16x16x32_bf16(
                wout[mo][kt], bh, oacc[mo], 0, 0, 0);
    }
    #pragma unroll
    for (int mo = 0; mo < 2; ++mo)
        #pragma unroll
        for (int r = 0; r < 4; ++r) {
            const int o = (wid * 2 + mo) * 16 + q * 4 + r;
            out[(size_t)(bblk + n15) * NOUT + o] = oacc[mo][r];
        }
}

extern "C" void kernel_launch(void* const* d_in, const int* in_sizes, int n_in,
                              void* d_out, int out_size, void* d_ws, size_t ws_size,
                              hipStream_t stream) {
    const float* x     = (const float*)d_in[0];
    const float* W_in  = (const float*)d_in[1];
    const float* b_in  = (const float*)d_in[2];
    const float* W_rec = (const float*)d_in[3];
    const float* W_out = (const float*)d_in[4];
    const float* b_out = (const float*)d_in[5];
    float* out = (float*)d_out;

    elman_mfma<<<NBLK, 256, 0, stream>>>(x, W_in, b_in, W_rec, W_out, b_out, out);
}

// Round 3
// 2274.912 us; speedup vs baseline: 1.9997x; 1.1492x over previous
//
#include <hip/hip_runtime.h>
#include <hip/hip_bf16.h>

// Elman RNN, round 3.
// Phase 1 (full chip, 256 blocks): xin[t][b][h] = bf16(x[b,t,:].W_in[h,:] + b_in[h])
//          stored in d_ws (134 MB). MFMA, computed transposed (m=hidden, n=batch)
//          so each lane's 4 accs are 4 consecutive h -> uint2 store.
// Phase 2 (8 blocks x 16 batch rows): scan h' = sigmoid(xin_t + h.W_rec^T).
//          W_rec A-frags in registers (128 VGPR), h ping-pongs through padded LDS
//          (C-layout write -> B-layout read), xin tile prefetched 1 step ahead.
// Fallback: if ws_size < 134 MB, the round-2 fully-fused kernel.

#define BATCH 128
#define SEQ   2048
#define NIN   128
#define NH    256
#define NOUT  128

#define BTILE 16
#define NBLK  (BATCH / BTILE)      // 8
#define HPITCH 264                 // 256 + 8 pad (bf16 elems): b128 reads conflict-free
#define XPITCH 136
#define TCHUNK 64                  // timesteps per pre-GEMM block

typedef __attribute__((ext_vector_type(8))) short short8;
typedef __attribute__((ext_vector_type(4))) float f32x4;

__device__ __forceinline__ ushort f2bf(float f) {
    union { float f; uint u; } v; v.f = f;
    uint r = v.u + 0x7fffu + ((v.u >> 16) & 1u);   // RNE
    return (ushort)(r >> 16);
}

__device__ __forceinline__ short8 load_wfrag(const float* __restrict__ W, int ld,
                                             int row, int col) {
    const float4* p = (const float4*)(W + (size_t)row * ld + col);
    float4 a = p[0], b = p[1];
    union { short8 v; ushort u[8]; } r;
    r.u[0] = f2bf(a.x); r.u[1] = f2bf(a.y); r.u[2] = f2bf(a.z); r.u[3] = f2bf(a.w);
    r.u[4] = f2bf(b.x); r.u[5] = f2bf(b.y); r.u[6] = f2bf(b.z); r.u[7] = f2bf(b.w);
    return r.v;
}

__device__ __forceinline__ float bfhi2f(uint u) {   // high 16 bits -> float
    union { uint u; float f; } v; v.u = u & 0xffff0000u; return v.f;
}
__device__ __forceinline__ float bflo2f(uint u) {
    union { uint u; float f; } v; v.u = u << 16; return v.f;
}

// ---------------- Phase 1: xin = x.W_in^T + b_in ----------------
__global__ __launch_bounds__(256, 1)
void xin_gemm(const float* __restrict__ x,
              const float* __restrict__ W_in,
              const float* __restrict__ b_in,
              ushort* __restrict__ xin) {
    const int tid  = threadIdx.x;
    const int lane = tid & 63;
    const int wid  = tid >> 6;
    const int n15  = lane & 15;
    const int q    = lane >> 4;
    const int bblk = blockIdx.x * BTILE;      // 8
    const int t0   = blockIdx.y * TCHUNK;     // 32

    short8 win[4][4];
    float  bias[4][4];
    #pragma unroll
    for (int mt = 0; mt < 4; ++mt) {
        const int row = (wid * 4 + mt) * 16 + n15;
        #pragma unroll
        for (int kt = 0; kt < 4; ++kt)
            win[mt][kt] = load_wfrag(W_in, NIN, row, kt * 32 + q * 8);
        #pragma unroll
        for (int r = 0; r < 4; ++r)
            bias[mt][r] = b_in[(wid * 4 + mt) * 16 + q * 4 + r];
    }

    const size_t xrow = (size_t)(bblk + n15) * SEQ * NIN;

    #pragma unroll 1
    for (int tt = 0; tt < TCHUNK; ++tt) {
        const int t = t0 + tt;
        short8 bx[4];
        #pragma unroll
        for (int kt = 0; kt < 4; ++kt) {
            const float4* p = (const float4*)(x + xrow + (size_t)t * NIN + kt * 32 + q * 8);
            float4 a = p[0], b = p[1];
            union { short8 v; ushort u[8]; } r;
            r.u[0] = f2bf(a.x); r.u[1] = f2bf(a.y); r.u[2] = f2bf(a.z); r.u[3] = f2bf(a.w);
            r.u[4] = f2bf(b.x); r.u[5] = f2bf(b.y); r.u[6] = f2bf(b.z); r.u[7] = f2bf(b.w);
            bx[kt] = r.v;
        }
        f32x4 acc[4];
        #pragma unroll
        for (int mt = 0; mt < 4; ++mt) {
            acc[mt][0] = bias[mt][0]; acc[mt][1] = bias[mt][1];
            acc[mt][2] = bias[mt][2]; acc[mt][3] = bias[mt][3];
        }
        #pragma unroll
        for (int kt = 0; kt < 4; ++kt)
            #pragma unroll
            for (int mt = 0; mt < 4; ++mt)
                acc[mt] = __builtin_amdgcn_mfma_f32_16x16x32_bf16(
                    win[mt][kt], bx[kt], acc[mt], 0, 0, 0);
        #pragma unroll
        for (int mt = 0; mt < 4; ++mt) {
            uint2 w;
            w.x = (uint)f2bf(acc[mt][0]) | ((uint)f2bf(acc[mt][1]) << 16);
            w.y = (uint)f2bf(acc[mt][2]) | ((uint)f2bf(acc[mt][3]) << 16);
            *(uint2*)&xin[(size_t)t * BATCH * NH + (size_t)(bblk + n15) * NH
                          + (wid * 4 + mt) * 16 + q * 4] = w;
        }
    }
}

// ---------------- Phase 2: sequential scan + output projection ----------------
__global__ __launch_bounds__(256, 1)
void elman_scan(const ushort* __restrict__ xin,
                const float* __restrict__ W_rec,
                const float* __restrict__ W_out,
                const float* __restrict__ b_out,
                float* __restrict__ out) {
    const int tid  = threadIdx.x;
    const int lane = tid & 63;
    const int wid  = tid >> 6;
    const int n15  = lane & 15;
    const int q    = lane >> 4;
    const int bblk = blockIdx.x * BTILE;

    __shared__ __align__(16) ushort hlds[2][BTILE * HPITCH];  // 2 x 8448 B

    // W_rec A-fragments in registers (128 VGPRs)
    short8 wrec[4][8];
    #pragma unroll
    for (int mt = 0; mt < 4; ++mt) {
        const int row = (wid * 4 + mt) * 16 + n15;
        #pragma unroll
        for (int kt = 0; kt < 8; ++kt)
            wrec[mt][kt] = load_wfrag(W_rec, NH, row, kt * 32 + q * 8);
    }

    // h0 = 0
    for (int i = tid; i < BTILE * HPITCH / 2; i += 256)
        ((uint*)hlds[0])[i] = 0u;

    // xin address for this lane: [t][bblk+n15][h = (wid*4+mt)*16 + q*4]
    const size_t xoff = (size_t)(bblk + n15) * NH + q * 4;
    uint2 xin_cur[4], xin_nxt[4];
    #pragma unroll
    for (int mt = 0; mt < 4; ++mt)
        xin_cur[mt] = *(const uint2*)&xin[xoff + (wid * 4 + mt) * 16];

    __syncthreads();

    #pragma unroll 1
    for (int t = 0; t < SEQ; ++t) {
        const int cur = t & 1, nxt = cur ^ 1;

        // prefetch xin_{t+1} (clamped; last prefetch unused)
        const int tp = (t + 1 < SEQ) ? (t + 1) : (SEQ - 1);
        const size_t pb = (size_t)tp * BATCH * NH + xoff;
        #pragma unroll
        for (int mt = 0; mt < 4; ++mt)
            xin_nxt[mt] = *(const uint2*)&xin[pb + (wid * 4 + mt) * 16];

        // B-fragments of h_t
        short8 bh[8];
        #pragma unroll
        for (int kt = 0; kt < 8; ++kt)
            bh[kt] = *(const short8*)&hlds[cur][n15 * HPITCH + kt * 32 + q * 8];

        // acc init = xin (bias already folded in)
        f32x4 acc[4];
        #pragma unroll
        for (int mt = 0; mt < 4; ++mt) {
            acc[mt][0] = bflo2f(xin_cur[mt].x);
            acc[mt][1] = bfhi2f(xin_cur[mt].x);
            acc[mt][2] = bflo2f(xin_cur[mt].y);
            acc[mt][3] = bfhi2f(xin_cur[mt].y);
        }
        #pragma unroll
        for (int kt = 0; kt < 8; ++kt)
            #pragma unroll
            for (int mt = 0; mt < 4; ++mt)
                acc[mt] = __builtin_amdgcn_mfma_f32_16x16x32_bf16(
                    wrec[mt][kt], bh[kt], acc[mt], 0, 0, 0);

        // sigmoid + pack + write h_{t+1}
        #pragma unroll
        for (int mt = 0; mt < 4; ++mt) {
            float h0 = __builtin_amdgcn_rcpf(1.0f + __expf(-acc[mt][0]));
            float h1 = __builtin_amdgcn_rcpf(1.0f + __expf(-acc[mt][1]));
            float h2 = __builtin_amdgcn_rcpf(1.0f + __expf(-acc[mt][2]));
            float h3 = __builtin_amdgcn_rcpf(1.0f + __expf(-acc[mt][3]));
            uint2 w;
            w.x = (uint)f2bf(h0) | ((uint)f2bf(h1) << 16);
            w.y = (uint)f2bf(h2) | ((uint)f2bf(h3) << 16);
            *(uint2*)&hlds[nxt][n15 * HPITCH + (wid * 4 + mt) * 16 + q * 4] = w;
        }

        #pragma unroll
        for (int mt = 0; mt < 4; ++mt) xin_cur[mt] = xin_nxt[mt];

        __syncthreads();
    }

    // ---- output projection from hlds[0] (SEQ even) ----
    short8 wout[2][8];
    float  bo[2][4];
    #pragma unroll
    for (int mo = 0; mo < 2; ++mo) {
        const int row = (wid * 2 + mo) * 16 + n15;
        #pragma unroll
        for (int kt = 0; kt < 8; ++kt)
            wout[mo][kt] = load_wfrag(W_out, NH, row, kt * 32 + q * 8);
        #pragma unroll
        for (int r = 0; r < 4; ++r)
            bo[mo][r] = b_out[(wid * 2 + mo) * 16 + q * 4 + r];
    }
    f32x4 oacc[2];
    #pragma unroll
    for (int mo = 0; mo < 2; ++mo) {
        oacc[mo][0] = bo[mo][0]; oacc[mo][1] = bo[mo][1];
        oacc[mo][2] = bo[mo][2]; oacc[mo][3] = bo[mo][3];
    }
    #pragma unroll
    for (int kt = 0; kt < 8; ++kt) {
        short8 bh = *(const short8*)&hlds[0][n15 * HPITCH + kt * 32 + q * 8];
        #pragma unroll
        for (int mo = 0; mo < 2; ++mo)
            oacc[mo] = __builtin_amdgcn_mfma_f32_16x16x32_bf16(
                wout[mo][kt], bh, oacc[mo], 0, 0, 0);
    }
    #pragma unroll
    for (int mo = 0; mo < 2; ++mo)
        #pragma unroll
        for (int r = 0; r < 4; ++r) {
            const int o = (wid * 2 + mo) * 16 + q * 4 + r;
            out[(size_t)(bblk + n15) * NOUT + o] = oacc[mo][r];
        }
}

// ---------------- Fallback (round-2 fused kernel) if ws too small ----------------
__global__ __launch_bounds__(256, 1)
void elman_mfma(const float* __restrict__ x,
                const float* __restrict__ W_in,
                const float* __restrict__ b_in,
                const float* __restrict__ W_rec,
                const float* __restrict__ W_out,
                const float* __restrict__ b_out,
                float* __restrict__ out) {
    const int tid  = threadIdx.x;
    const int lane = tid & 63;
    const int wid  = tid >> 6;
    const int n15  = lane & 15;
    const int q    = lane >> 4;
    const int bblk = blockIdx.x * BTILE;

    __shared__ __align__(16) ushort hlds[2][BTILE * HPITCH];
    __shared__ __align__(16) ushort xlds[2][BTILE * XPITCH];

    short8 wrec[4][8];
    short8 win[4][4];
    float  bias[4][4];
    #pragma unroll
    for (int mt = 0; mt < 4; ++mt) {
        const int row = (wid * 4 + mt) * 16 + n15;
        #pragma unroll
        for (int kt = 0; kt < 8; ++kt)
            wrec[mt][kt] = load_wfrag(W_rec, NH, row, kt * 32 + q * 8);
        #pragma unroll
        for (int kt = 0; kt < 4; ++kt)
            win[mt][kt] = load_wfrag(W_in, NIN, row, kt * 32 + q * 8);
        #pragma unroll
        for (int r = 0; r < 4; ++r)
            bias[mt][r] = b_in[(wid * 4 + mt) * 16 + q * 4 + r];
    }

    for (int i = tid; i < BTILE * HPITCH / 2; i += 256)
        ((uint*)hlds[0])[i] = 0u;

    const int xr = tid >> 4;
    const int xc = (tid & 15) * 8;
    const size_t xbase = ((size_t)(bblk + xr)) * SEQ * NIN + xc;
    {
        const float4* p = (const float4*)(x + xbase);
        float4 a = p[0], b = p[1];
        union { uint4 u4; ushort s[8]; } px;
        px.s[0] = f2bf(a.x); px.s[1] = f2bf(a.y); px.s[2] = f2bf(a.z); px.s[3] = f2bf(a.w);
        px.s[4] = f2bf(b.x); px.s[5] = f2bf(b.y); px.s[6] = f2bf(b.z); px.s[7] = f2bf(b.w);
        *(uint4*)&xlds[0][xr * XPITCH + xc] = px.u4;
    }
    __syncthreads();

    #pragma unroll 1
    for (int t = 0; t < SEQ; ++t) {
        const int cur = t & 1, nxt = cur ^ 1;
        float4 xp0{}, xp1{};
        if (t + 1 < SEQ) {
            const float4* p = (const float4*)(x + xbase + (size_t)(t + 1) * NIN);
            xp0 = p[0]; xp1 = p[1];
        }
        short8 bx[4], bh[8];
        #pragma unroll
        for (int kt = 0; kt < 4; ++kt)
            bx[kt] = *(const short8*)&xlds[cur][n15 * XPITCH + kt * 32 + q * 8];
        #pragma unroll
        for (int kt = 0; kt < 8; ++kt)
            bh[kt] = *(const short8*)&hlds[cur][n15 * HPITCH + kt * 32 + q * 8];
        f32x4 acc[4];
        #pragma unroll
        for (int mt = 0; mt < 4; ++mt) {
            acc[mt][0] = bias[mt][0]; acc[mt][1] = bias[mt][1];
            acc[mt][2] = bias[mt][2]; acc[mt][3] = bias[mt][3];
        }
        #pragma unroll
        for (int kt = 0; kt < 4; ++kt)
            #pragma unroll
            for (int mt = 0; mt < 4; ++mt)
                acc[mt] = __builtin_amdgcn_mfma_f32_16x16x32_bf16(
                    win[mt][kt], bx[kt], acc[mt], 0, 0, 0);
        #pragma unroll
        for (int kt = 0; kt < 8; ++kt)
            #pragma unroll
            for (int mt = 0; mt < 4; ++mt)
                acc[mt] = __builtin_amdgcn_mfma_f32_16x16x32_bf16(
                    wrec[mt][kt], bh[kt], acc[mt], 0, 0, 0);
        #pragma unroll
        for (int mt = 0; mt < 4; ++mt) {
            float h0 = 1.0f / (1.0f + __expf(-acc[mt][0]));
            float h1 = 1.0f / (1.0f + __expf(-acc[mt][1]));
            float h2 = 1.0f / (1.0f + __expf(-acc[mt][2]));
            float h3 = 1.0f / (1.0f + __expf(-acc[mt][3]));
            uint2 w;
            w.x = (uint)f2bf(h0) | ((uint)f2bf(h1) << 16);
            w.y = (uint)f2bf(h2) | ((uint)f2bf(h3) << 16);
            *(uint2*)&hlds[nxt][n15 * HPITCH + (wid * 4 + mt) * 16 + q * 4] = w;
        }
        if (t + 1 < SEQ) {
            union { uint4 u4; ushort s[8]; } px;
            px.s[0] = f2bf(xp0.x); px.s[1] = f2bf(xp0.y);
            px.s[2] = f2bf(xp0.z); px.s[3] = f2bf(xp0.w);
            px.s[4] = f2bf(xp1.x); px.s[5] = f2bf(xp1.y);
            px.s[6] = f2bf(xp1.z); px.s[7] = f2bf(xp1.w);
            *(uint4*)&xlds[nxt][xr * XPITCH + xc] = px.u4;
        }
        __syncthreads();
    }

    short8 wout[2][8];
    float  bo[2][4];
    #pragma unroll
    for (int mo = 0; mo < 2; ++mo) {
        const int row = (wid * 2 + mo) * 16 + n15;
        #pragma unroll
        for (int kt = 0; kt < 8; ++kt)
            wout[mo][kt] = load_wfrag(W_out, NH, row, kt * 32 + q * 8);
        #pragma unroll
        for (int r = 0; r < 4; ++r)
            bo[mo][r] = b_out[(wid * 2 + mo) * 16 + q * 4 + r];
    }
    f32x4 oacc[2];
    #pragma unroll
    for (int mo = 0; mo < 2; ++mo) {
        oacc[mo][0] = bo[mo][0]; oacc[mo][1] = bo[mo][1];
        oacc[mo][2] = bo[mo][2]; oacc[mo][3] = bo[mo][3];
    }
    #pragma unroll
    for (int kt = 0; kt < 8; ++kt) {
        short8 bh = *(const short8*)&hlds[0][n15 * HPITCH + kt * 32 + q * 8];
        #pragma unroll
        for (int mo = 0; mo < 2; ++mo)
            oacc[mo] = __builtin_amdgcn_mfma_f32_16x16x32_bf16(
                wout[mo][kt], bh, oacc[mo], 0, 0, 0);
    }
    #pragma unroll
    for (int mo = 0; mo < 2; ++mo)
        #pragma unroll
        for (int r = 0; r < 4; ++r) {
            const int o = (wid * 2 + mo) * 16 + q * 4 + r;
            out[(size_t)(bblk + n15) * NOUT + o] = oacc[mo][r];
        }
}

extern "C" void kernel_launch(void* const* d_in, const int* in_sizes, int n_in,
                              void* d_out, int out_size, void* d_ws, size_t ws_size,
                              hipStream_t stream) {
    const float* x     = (const float*)d_in[0];
    const float* W_in  = (const float*)d_in[1];
    const float* b_in  = (const float*)d_in[2];
    const float* W_rec = (const float*)d_in[3];
    const float* W_out = (const float*)d_in[4];
    const float* b_out = (const float*)d_in[5];
    float* out = (float*)d_out;

    const size_t need = (size_t)SEQ * BATCH * NH * sizeof(ushort);  // 134 MB
    if (ws_size >= need) {
        ushort* xin = (ushort*)d_ws;
        dim3 g1(NBLK, SEQ / TCHUNK);   // 8 x 32 = 256 blocks
        xin_gemm<<<g1, 256, 0, stream>>>(x, W_in, b_in, xin);
        elman_scan<<<NBLK, 256, 0, stream>>>(xin, W_rec, W_out, b_out, out);
    } else {
        elman_mfma<<<NBLK, 256, 0, stream>>>(x, W_in, b_in, W_rec, W_out, b_out, out);
    }
}

// Round 4
// 1462.762 us; speedup vs baseline: 3.1100x; 1.5552x over previous
//
#include <hip/hip_runtime.h>
#include <hip/hip_bf16.h>

// Elman RNN, round 4.
// Phase 1 (1024 blocks): xin[t][b][h] = bf16( log2e * (x[b,t,:].W_in[h,:] + b_in[h]) )
//   into d_ws. log2(e) is folded into the weights so the scan's sigmoid needs no mul:
//   sigmoid(a) = rcp(1 + exp2(-log2e*a)).
// Phase 2 (8 blocks x 16 batch, 512 threads = 8 waves = 2 waves/SIMD):
//   scan h' = sigmoid(xin_t + h.W_rec^T). Each wave owns 2 hidden m-tiles; with 2
//   waves per SIMD the MFMA pipe of one wave overlaps the sigmoid VALU chain of the
//   other (m114 co-scheduling), so step time ~ max(pipe) instead of sum(pipes).
//   W_rec A-frags (scaled) in registers; h ping-pongs through padded LDS
//   (C-layout write -> B-layout read); xin prefetched one step ahead.

#define BATCH 128
#define SEQ   2048
#define NIN   128
#define NH    256
#define NOUT  128

#define BTILE 16
#define NBLK  (BATCH / BTILE)      // 8
#define HPITCH 264                 // 256 + 8 pad (bf16): row stride = 4 banks
#define XPITCH 136
#define TCHUNK 16                  // timesteps per phase-1 block
#define LOG2E 1.4426950408889634f

typedef __attribute__((ext_vector_type(8))) short short8;
typedef __attribute__((ext_vector_type(4))) float f32x4;

__device__ __forceinline__ ushort f2bf(float f) {
    union { float f; uint u; } v; v.f = f;
    uint r = v.u + 0x7fffu + ((v.u >> 16) & 1u);   // RNE
    return (ushort)(r >> 16);
}

__device__ __forceinline__ uint pk_bf16(float a, float b) {
    float2 p; p.x = a; p.y = b;
    __hip_bfloat162 h = __float22bfloat162_rn(p);
    union { __hip_bfloat162 h; uint u; } v; v.h = h; return v.u;
}

// 8-wide (k) bf16 A-fragment from fp32 row-major W, optionally pre-scaled.
__device__ __forceinline__ short8 load_wfrag_s(const float* __restrict__ W, int ld,
                                               int row, int col, float scale) {
    const float4* p = (const float4*)(W + (size_t)row * ld + col);
    float4 a = p[0], b = p[1];
    union { short8 v; ushort u[8]; } r;
    r.u[0] = f2bf(a.x * scale); r.u[1] = f2bf(a.y * scale);
    r.u[2] = f2bf(a.z * scale); r.u[3] = f2bf(a.w * scale);
    r.u[4] = f2bf(b.x * scale); r.u[5] = f2bf(b.y * scale);
    r.u[6] = f2bf(b.z * scale); r.u[7] = f2bf(b.w * scale);
    return r.v;
}

__device__ __forceinline__ float bfhi2f(uint u) {
    union { uint u; float f; } v; v.u = u & 0xffff0000u; return v.f;
}
__device__ __forceinline__ float bflo2f(uint u) {
    union { uint u; float f; } v; v.u = u << 16; return v.f;
}

// ---------------- Phase 1: xin = log2e*(x.W_in^T + b_in) ----------------
__global__ __launch_bounds__(256, 1)
void xin_gemm(const float* __restrict__ x,
              const float* __restrict__ W_in,
              const float* __restrict__ b_in,
              ushort* __restrict__ xin) {
    const int tid  = threadIdx.x;
    const int lane = tid & 63;
    const int wid  = tid >> 6;
    const int n15  = lane & 15;
    const int q    = lane >> 4;
    const int bblk = blockIdx.x * BTILE;
    const int t0   = blockIdx.y * TCHUNK;

    short8 win[4][4];
    float  bias[4][4];
    #pragma unroll
    for (int mt = 0; mt < 4; ++mt) {
        const int row = (wid * 4 + mt) * 16 + n15;
        #pragma unroll
        for (int kt = 0; kt < 4; ++kt)
            win[mt][kt] = load_wfrag_s(W_in, NIN, row, kt * 32 + q * 8, LOG2E);
        #pragma unroll
        for (int r = 0; r < 4; ++r)
            bias[mt][r] = LOG2E * b_in[(wid * 4 + mt) * 16 + q * 4 + r];
    }

    const size_t xrow = (size_t)(bblk + n15) * SEQ * NIN;

    #pragma unroll 1
    for (int tt = 0; tt < TCHUNK; ++tt) {
        const int t = t0 + tt;
        short8 bx[4];
        #pragma unroll
        for (int kt = 0; kt < 4; ++kt) {
            const float4* p = (const float4*)(x + xrow + (size_t)t * NIN + kt * 32 + q * 8);
            float4 a = p[0], b = p[1];
            union { short8 v; ushort u[8]; } r;
            r.u[0] = f2bf(a.x); r.u[1] = f2bf(a.y); r.u[2] = f2bf(a.z); r.u[3] = f2bf(a.w);
            r.u[4] = f2bf(b.x); r.u[5] = f2bf(b.y); r.u[6] = f2bf(b.z); r.u[7] = f2bf(b.w);
            bx[kt] = r.v;
        }
        f32x4 acc[4];
        #pragma unroll
        for (int mt = 0; mt < 4; ++mt) {
            acc[mt][0] = bias[mt][0]; acc[mt][1] = bias[mt][1];
            acc[mt][2] = bias[mt][2]; acc[mt][3] = bias[mt][3];
        }
        #pragma unroll
        for (int kt = 0; kt < 4; ++kt)
            #pragma unroll
            for (int mt = 0; mt < 4; ++mt)
                acc[mt] = __builtin_amdgcn_mfma_f32_16x16x32_bf16(
                    win[mt][kt], bx[kt], acc[mt], 0, 0, 0);
        #pragma unroll
        for (int mt = 0; mt < 4; ++mt) {
            uint2 w;
            w.x = pk_bf16(acc[mt][0], acc[mt][1]);
            w.y = pk_bf16(acc[mt][2], acc[mt][3]);
            *(uint2*)&xin[(size_t)t * BATCH * NH + (size_t)(bblk + n15) * NH
                          + (wid * 4 + mt) * 16 + q * 4] = w;
        }
    }
}

// ---------------- Phase 2: sequential scan + output projection ----------------
__global__ __launch_bounds__(512, 2)
void elman_scan(const ushort* __restrict__ xin,
                const float* __restrict__ W_rec,
                const float* __restrict__ W_out,
                const float* __restrict__ b_out,
                float* __restrict__ out) {
    const int tid  = threadIdx.x;
    const int lane = tid & 63;
    const int wid  = tid >> 6;          // 0..7
    const int n15  = lane & 15;
    const int q    = lane >> 4;
    const int bblk = blockIdx.x * BTILE;

    __shared__ __align__(16) ushort hlds[2][BTILE * HPITCH];  // 2 x 8448 B

    // W_rec A-fragments (scaled by log2e) — 2 m-tiles per wave = 64 VGPRs
    short8 wrec[2][8];
    #pragma unroll
    for (int mt = 0; mt < 2; ++mt) {
        const int row = (wid * 2 + mt) * 16 + n15;
        #pragma unroll
        for (int kt = 0; kt < 8; ++kt)
            wrec[mt][kt] = load_wfrag_s(W_rec, NH, row, kt * 32 + q * 8, LOG2E);
    }

    // h0 = 0
    for (int i = tid; i < BTILE * HPITCH / 2; i += 512)
        ((uint*)hlds[0])[i] = 0u;

    // xin element this lane consumes: [t][bblk+n15][(wid*2+mt)*16 + q*4 .. +3]
    const size_t xoff = (size_t)(bblk + n15) * NH + q * 4;
    uint2 xin_cur[2], xin_nxt[2];
    #pragma unroll
    for (int mt = 0; mt < 2; ++mt)
        xin_cur[mt] = *(const uint2*)&xin[xoff + (wid * 2 + mt) * 16];

    __syncthreads();

    #pragma unroll 1
    for (int t = 0; t < SEQ; ++t) {
        const int cur = t & 1, nxt = cur ^ 1;

        // prefetch xin_{t+1} (clamped)
        const int tp = (t + 1 < SEQ) ? (t + 1) : (SEQ - 1);
        const size_t pb = (size_t)tp * BATCH * NH + xoff;
        #pragma unroll
        for (int mt = 0; mt < 2; ++mt)
            xin_nxt[mt] = *(const uint2*)&xin[pb + (wid * 2 + mt) * 16];

        // B-fragments of h_t
        short8 bh[8];
        #pragma unroll
        for (int kt = 0; kt < 8; ++kt)
            bh[kt] = *(const short8*)&hlds[cur][n15 * HPITCH + kt * 32 + q * 8];

        // acc init = scaled xin (bias folded), then recurrent MFMAs
        f32x4 acc[2];
        #pragma unroll
        for (int mt = 0; mt < 2; ++mt) {
            acc[mt][0] = bflo2f(xin_cur[mt].x);
            acc[mt][1] = bfhi2f(xin_cur[mt].x);
            acc[mt][2] = bflo2f(xin_cur[mt].y);
            acc[mt][3] = bfhi2f(xin_cur[mt].y);
        }
        #pragma unroll
        for (int kt = 0; kt < 8; ++kt)
            #pragma unroll
            for (int mt = 0; mt < 2; ++mt)
                acc[mt] = __builtin_amdgcn_mfma_f32_16x16x32_bf16(
                    wrec[mt][kt], bh[kt], acc[mt], 0, 0, 0);

        // sigmoid(a) = rcp(1 + 2^(-z)) with z = log2e*a already in acc
        #pragma unroll
        for (int mt = 0; mt < 2; ++mt) {
            float h0 = __builtin_amdgcn_rcpf(1.0f + __builtin_amdgcn_exp2f(-acc[mt][0]));
            float h1 = __builtin_amdgcn_rcpf(1.0f + __builtin_amdgcn_exp2f(-acc[mt][1]));
            float h2 = __builtin_amdgcn_rcpf(1.0f + __builtin_amdgcn_exp2f(-acc[mt][2]));
            float h3 = __builtin_amdgcn_rcpf(1.0f + __builtin_amdgcn_exp2f(-acc[mt][3]));
            uint2 w;
            w.x = pk_bf16(h0, h1);
            w.y = pk_bf16(h2, h3);
            *(uint2*)&hlds[nxt][n15 * HPITCH + (wid * 2 + mt) * 16 + q * 4] = w;
        }

        #pragma unroll
        for (int mt = 0; mt < 2; ++mt) xin_cur[mt] = xin_nxt[mt];

        __syncthreads();
    }

    // ---- output projection from hlds[0] (SEQ even): wave wid owns m-tile wid ----
    short8 wout[8];
    float  bo[4];
    {
        const int row = wid * 16 + n15;
        #pragma unroll
        for (int kt = 0; kt < 8; ++kt)
            wout[kt] = load_wfrag_s(W_out, NH, row, kt * 32 + q * 8, 1.0f);
        #pragma unroll
        for (int r = 0; r < 4; ++r)
            bo[r] = b_out[wid * 16 + q * 4 + r];
    }
    f32x4 oacc;
    oacc[0] = bo[0]; oacc[1] = bo[1]; oacc[2] = bo[2]; oacc[3] = bo[3];
    #pragma unroll
    for (int kt = 0; kt < 8; ++kt) {
        short8 bh = *(const short8*)&hlds[0][n15 * HPITCH + kt * 32 + q * 8];
        oacc = __builtin_amdgcn_mfma_f32_16x16x32_bf16(wout[kt], bh, oacc, 0, 0, 0);
    }
    #pragma unroll
    for (int r = 0; r < 4; ++r) {
        const int o = wid * 16 + q * 4 + r;
        out[(size_t)(bblk + n15) * NOUT + o] = oacc[r];
    }
}

// ---------------- Fallback (fully fused, round-2) if ws too small ----------------
__global__ __launch_bounds__(256, 1)
void elman_mfma(const float* __restrict__ x,
                const float* __restrict__ W_in,
                const float* __restrict__ b_in,
                const float* __restrict__ W_rec,
                const float* __restrict__ W_out,
                const float* __restrict__ b_out,
                float* __restrict__ out) {
    const int tid  = threadIdx.x;
    const int lane = tid & 63;
    const int wid  = tid >> 6;
    const int n15  = lane & 15;
    const int q    = lane >> 4;
    const int bblk = blockIdx.x * BTILE;

    __shared__ __align__(16) ushort hlds[2][BTILE * HPITCH];
    __shared__ __align__(16) ushort xlds[2][BTILE * XPITCH];

    short8 wrec[4][8];
    short8 win[4][4];
    float  bias[4][4];
    #pragma unroll
    for (int mt = 0; mt < 4; ++mt) {
        const int row = (wid * 4 + mt) * 16 + n15;
        #pragma unroll
        for (int kt = 0; kt < 8; ++kt)
            wrec[mt][kt] = load_wfrag_s(W_rec, NH, row, kt * 32 + q * 8, 1.0f);
        #pragma unroll
        for (int kt = 0; kt < 4; ++kt)
            win[mt][kt] = load_wfrag_s(W_in, NIN, row, kt * 32 + q * 8, 1.0f);
        #pragma unroll
        for (int r = 0; r < 4; ++r)
            bias[mt][r] = b_in[(wid * 4 + mt) * 16 + q * 4 + r];
    }

    for (int i = tid; i < BTILE * HPITCH / 2; i += 256)
        ((uint*)hlds[0])[i] = 0u;

    const int xr = tid >> 4;
    const int xc = (tid & 15) * 8;
    const size_t xbase = ((size_t)(bblk + xr)) * SEQ * NIN + xc;
    {
        const float4* p = (const float4*)(x + xbase);
        float4 a = p[0], b = p[1];
        union { uint4 u4; ushort s[8]; } px;
        px.s[0] = f2bf(a.x); px.s[1] = f2bf(a.y); px.s[2] = f2bf(a.z); px.s[3] = f2bf(a.w);
        px.s[4] = f2bf(b.x); px.s[5] = f2bf(b.y); px.s[6] = f2bf(b.z); px.s[7] = f2bf(b.w);
        *(uint4*)&xlds[0][xr * XPITCH + xc] = px.u4;
    }
    __syncthreads();

    #pragma unroll 1
    for (int t = 0; t < SEQ; ++t) {
        const int cur = t & 1, nxt = cur ^ 1;
        float4 xp0{}, xp1{};
        if (t + 1 < SEQ) {
            const float4* p = (const float4*)(x + xbase + (size_t)(t + 1) * NIN);
            xp0 = p[0]; xp1 = p[1];
        }
        short8 bx[4], bh[8];
        #pragma unroll
        for (int kt = 0; kt < 4; ++kt)
            bx[kt] = *(const short8*)&xlds[cur][n15 * XPITCH + kt * 32 + q * 8];
        #pragma unroll
        for (int kt = 0; kt < 8; ++kt)
            bh[kt] = *(const short8*)&hlds[cur][n15 * HPITCH + kt * 32 + q * 8];
        f32x4 acc[4];
        #pragma unroll
        for (int mt = 0; mt < 4; ++mt) {
            acc[mt][0] = bias[mt][0]; acc[mt][1] = bias[mt][1];
            acc[mt][2] = bias[mt][2]; acc[mt][3] = bias[mt][3];
        }
        #pragma unroll
        for (int kt = 0; kt < 4; ++kt)
            #pragma unroll
            for (int mt = 0; mt < 4; ++mt)
                acc[mt] = __builtin_amdgcn_mfma_f32_16x16x32_bf16(
                    win[mt][kt], bx[kt], acc[mt], 0, 0, 0);
        #pragma unroll
        for (int kt = 0; kt < 8; ++kt)
            #pragma unroll
            for (int mt = 0; mt < 4; ++mt)
                acc[mt] = __builtin_amdgcn_mfma_f32_16x16x32_bf16(
                    wrec[mt][kt], bh[kt], acc[mt], 0, 0, 0);
        #pragma unroll
        for (int mt = 0; mt < 4; ++mt) {
            float h0 = 1.0f / (1.0f + __expf(-acc[mt][0]));
            float h1 = 1.0f / (1.0f + __expf(-acc[mt][1]));
            float h2 = 1.0f / (1.0f + __expf(-acc[mt][2]));
            float h3 = 1.0f / (1.0f + __expf(-acc[mt][3]));
            uint2 w;
            w.x = pk_bf16(h0, h1);
            w.y = pk_bf16(h2, h3);
            *(uint2*)&hlds[nxt][n15 * HPITCH + (wid * 4 + mt) * 16 + q * 4] = w;
        }
        if (t + 1 < SEQ) {
            union { uint4 u4; ushort s[8]; } px;
            px.s[0] = f2bf(xp0.x); px.s[1] = f2bf(xp0.y);
            px.s[2] = f2bf(xp0.z); px.s[3] = f2bf(xp0.w);
            px.s[4] = f2bf(xp1.x); px.s[5] = f2bf(xp1.y);
            px.s[6] = f2bf(xp1.z); px.s[7] = f2bf(xp1.w);
            *(uint4*)&xlds[nxt][xr * XPITCH + xc] = px.u4;
        }
        __syncthreads();
    }

    short8 wout[2][8];
    float  bo[2][4];
    #pragma unroll
    for (int mo = 0; mo < 2; ++mo) {
        const int row = (wid * 2 + mo) * 16 + n15;
        #pragma unroll
        for (int kt = 0; kt < 8; ++kt)
            wout[mo][kt] = load_wfrag_s(W_out, NH, row, kt * 32 + q * 8, 1.0f);
        #pragma unroll
        for (int r = 0; r < 4; ++r)
            bo[mo][r] = b_out[(wid * 2 + mo) * 16 + q * 4 + r];
    }
    f32x4 oacc[2];
    #pragma unroll
    for (int mo = 0; mo < 2; ++mo) {
        oacc[mo][0] = bo[mo][0]; oacc[mo][1] = bo[mo][1];
        oacc[mo][2] = bo[mo][2]; oacc[mo][3] = bo[mo][3];
    }
    #pragma unroll
    for (int kt = 0; kt < 8; ++kt) {
        short8 bh = *(const short8*)&hlds[0][n15 * HPITCH + kt * 32 + q * 8];
        #pragma unroll
        for (int mo = 0; mo < 2; ++mo)
            oacc[mo] = __builtin_amdgcn_mfma_f32_16x16x32_bf16(
                wout[mo][kt], bh, oacc[mo], 0, 0, 0);
    }
    #pragma unroll
    for (int mo = 0; mo < 2; ++mo)
        #pragma unroll
        for (int r = 0; r < 4; ++r) {
            const int o = (wid * 2 + mo) * 16 + q * 4 + r;
            out[(size_t)(bblk + n15) * NOUT + o] = oacc[mo][r];
        }
}

extern "C" void kernel_launch(void* const* d_in, const int* in_sizes, int n_in,
                              void* d_out, int out_size, void* d_ws, size_t ws_size,
                              hipStream_t stream) {
    const float* x     = (const float*)d_in[0];
    const float* W_in  = (const float*)d_in[1];
    const float* b_in  = (const float*)d_in[2];
    const float* W_rec = (const float*)d_in[3];
    const float* W_out = (const float*)d_in[4];
    const float* b_out = (const float*)d_in[5];
    float* out = (float*)d_out;

    const size_t need = (size_t)SEQ * BATCH * NH * sizeof(ushort);  // 134 MB
    if (ws_size >= need) {
        ushort* xin = (ushort*)d_ws;
        dim3 g1(NBLK, SEQ / TCHUNK);   // 8 x 128 = 1024 blocks
        xin_gemm<<<g1, 256, 0, stream>>>(x, W_in, b_in, xin);
        elman_scan<<<NBLK, 512, 0, stream>>>(xin, W_rec, W_out, b_out, out);
    } else {
        elman_mfma<<<NBLK, 256, 0, stream>>>(x, W_in, b_in, W_rec, W_out, b_out, out);
    }
}